// Round 2
// baseline (1518.845 us; speedup 1.0000x reference)
//
#include <hip/hip_runtime.h>

#define HD 64
#define ED 16
#define NU 100000
#define NI 200000
#define NN 300000
#define NE 1250000
#define NP 14

// ---------------------------------------------------------------------------
// LayerNorm, wave per row (lane = dim).
// FIRST: x from concat(user,item) fp32 inputs; zero d_out (the layer-1
//        accumulator — harness poisons it 0xAA) and the softmax denoms.
// !FIRST: x = d_out[i] (layer-1 output); after computing y, fuse the final-
//        mean prep: d_out[i] = (emb0[i] + x) / 3. Layer-2 aggregation then
//        atomically adds a*y[col]/3, leaving the final answer in d_out.
// ---------------------------------------------------------------------------
template <bool FIRST>
__global__ void ln_kernel(const float* __restrict__ user_emb,
                          const float* __restrict__ item_emb,
                          float* __restrict__ io,   // d_out accumulator
                          float* __restrict__ y,
                          float* __restrict__ d0,
                          float* __restrict__ d1)
{
    const int wave = (int)((blockIdx.x * blockDim.x + threadIdx.x) >> 6);
    const int lane = (int)(threadIdx.x & 63);
    if (wave >= NN) return;
    const size_t idx = (size_t)wave * HD + lane;

    const float e0i = (wave < NU) ? user_emb[idx]
                                  : item_emb[idx - (size_t)NU * HD];
    const float x = FIRST ? e0i : io[idx];

    float s = x, sq = x * x;
#pragma unroll
    for (int o = 32; o; o >>= 1) {
        s  += __shfl_xor(s, o, 64);
        sq += __shfl_xor(sq, o, 64);
    }
    const float mu  = s * (1.0f / 64.0f);
    const float var = sq * (1.0f / 64.0f) - mu * mu;
    const float inv = rsqrtf(var + 1e-5f);

    y[idx] = (x - mu) * inv;
    if (FIRST) {
        io[idx] = 0.0f;                       // zero layer-1 accumulator
    } else {
        io[idx] = (e0i + x) * (1.0f / 3.0f);  // (emb0 + out1)/3
    }
    if (lane == 0) { d0[wave] = 0.0f; d1[wave] = 0.0f; }
}

// ---------------------------------------------------------------------------
// Wave per edge: s0 = (y[r].y[c])/8 + exp(lam0)*(eig[r].eig[c]).
// Softmax is shift-invariant and scores are bounded (rows layernormed,
// ||y||=8; eig dot ~N(0,16)) so exp() can't overflow — skip segment-max.
// ---------------------------------------------------------------------------
__global__ void edge_score_kernel(const float* __restrict__ y,
                                  const float* __restrict__ eigs,
                                  const int* __restrict__ row,
                                  const int* __restrict__ col,
                                  const int* __restrict__ pt,
                                  const float* __restrict__ lambda0,
                                  const float* __restrict__ pemb,
                                  int layer,
                                  float* __restrict__ e0,
                                  float* __restrict__ d0,
                                  float* __restrict__ d1)
{
    const int lane = (int)(threadIdx.x & 63);
    const int wave = (int)((blockIdx.x * blockDim.x + threadIdx.x) >> 6);
    const int nw   = (int)((gridDim.x * blockDim.x) >> 6);
    const float lam = __expf(lambda0[layer]);

    for (int e = wave; e < NE; e += nw) {
        const int r = row[e];
        const int c = col[e];
        float p = y[(size_t)r * HD + lane] * y[(size_t)c * HD + lane] * 0.125f;
        if (lane < ED) {
            p += lam * eigs[(size_t)r * ED + lane] * eigs[(size_t)c * ED + lane];
        }
#pragma unroll
        for (int o = 32; o; o >>= 1) p += __shfl_xor(p, o, 64);
        if (lane == 0) {
            const float ex = __expf(p);
            e0[e] = ex;
            atomicAdd(&d0[r], ex);
            atomicAdd(&d1[r], __expf(pemb[layer * NP + pt[e]]));
        }
    }
}

// ---------------------------------------------------------------------------
// Wave per edge: a = 0.5*(e0/d0[r] + e1/d1[r]); out[r] += scale*a*y[c] via a
// 64-lane contiguous fp32 atomic burst (256 B per edge).
// ---------------------------------------------------------------------------
__global__ void edge_aggregate_kernel(const float* __restrict__ y,
                                      const int* __restrict__ row,
                                      const int* __restrict__ col,
                                      const int* __restrict__ pt,
                                      const float* __restrict__ pemb,
                                      int layer, float scale,
                                      const float* __restrict__ e0,
                                      const float* __restrict__ d0,
                                      const float* __restrict__ d1,
                                      float* __restrict__ out)
{
    const int lane = (int)(threadIdx.x & 63);
    const int wave = (int)((blockIdx.x * blockDim.x + threadIdx.x) >> 6);
    const int nw   = (int)((gridDim.x * blockDim.x) >> 6);

    for (int e = wave; e < NE; e += nw) {
        const int r = row[e];
        const int c = col[e];
        float a = 0.0f;
        if (lane == 0) {
            const float e1 = __expf(pemb[layer * NP + pt[e]]);
            a = scale * 0.5f * (e0[e] / d0[r] + e1 / d1[r]);
        }
        a = __shfl(a, 0, 64);
        atomicAdd(&out[(size_t)r * HD + lane], a * y[(size_t)c * HD + lane]);
    }
}

extern "C" void kernel_launch(void* const* d_in, const int* in_sizes, int n_in,
                              void* d_out, int out_size, void* d_ws, size_t ws_size,
                              hipStream_t stream)
{
    const float* user_emb = (const float*)d_in[0];
    const float* item_emb = (const float*)d_in[1];
    const float* eigs     = (const float*)d_in[2];
    const float* lambda0  = (const float*)d_in[3];
    const float* pemb     = (const float*)d_in[4];
    const int*   indices  = (const int*)d_in[5];
    const int*   ptype    = (const int*)d_in[6];
    const int*   row = indices;
    const int*   col = indices + NE;

    float* out = (float*)d_out;                // NN*HD fp32: persistent accum
    float* ws  = (float*)d_ws;
    float* y   = ws;                           // NN*HD fp32 (76.8 MB)
    float* d0  = y + (size_t)NN * HD;          // NN
    float* d1  = d0 + NN;                      // NN
    float* e0  = d1 + NN;                      // NE
    // total ws: ~84 MB

    const dim3 blk(256);
    const int ln_grid   = (NN * 64 + 255) / 256;   // wave per row
    const int edge_grid = 4096;                    // 16384 waves, grid-stride

    // ---- layer 0 ----
    ln_kernel<true><<<ln_grid, blk, 0, stream>>>(user_emb, item_emb, out, y, d0, d1);
    edge_score_kernel<<<edge_grid, blk, 0, stream>>>(y, eigs, row, col, ptype,
                                                     lambda0, pemb, 0, e0, d0, d1);
    edge_aggregate_kernel<<<edge_grid, blk, 0, stream>>>(y, row, col, ptype, pemb,
                                                         0, 1.0f, e0, d0, d1, out);
    // ---- layer 1 (ln fuses d_out := (emb0 + out1)/3) ----
    ln_kernel<false><<<ln_grid, blk, 0, stream>>>(user_emb, item_emb, out, y, d0, d1);
    edge_score_kernel<<<edge_grid, blk, 0, stream>>>(y, eigs, row, col, ptype,
                                                     lambda0, pemb, 1, e0, d0, d1);
    edge_aggregate_kernel<<<edge_grid, blk, 0, stream>>>(y, row, col, ptype, pemb,
                                                         1, 1.0f / 3.0f, e0, d0, d1, out);
}

// Round 3
// 1497.290 us; speedup vs baseline: 1.0144x; 1.0144x over previous
//
#include <hip/hip_runtime.h>
#include <hip/hip_bf16.h>

#define HD 64
#define ED 16
#define NU 100000
#define NI 200000
#define NN 300000
#define NE 1250000
#define NP 14

typedef __hip_bfloat16 bf16;
__device__ __forceinline__ float b2f(bf16 v) { return __bfloat162float(v); }

// ---------------------------------------------------------------------------
// LayerNorm, wave per row (lane = dim). Writes the bf16 gather table yb
// (128 B/row = exactly one cache line -> halves random-gather traffic vs
// fp32; absmax slack is 11x so bf16 rounding is affordable).
// FIRST: x from concat(user,item) fp32 inputs; zero d_out accumulator +
//        denoms; also builds the bf16 eig table (reused by both layers).
// !FIRST: x = d_out[i] (layer-1 out); fuse d_out[i] = (emb0 + x)/3 so the
//        layer-2 aggregation (scaled 1/3) leaves the final mean in d_out.
// ---------------------------------------------------------------------------
template <bool FIRST>
__global__ void ln_kernel(const float* __restrict__ user_emb,
                          const float* __restrict__ item_emb,
                          const float* __restrict__ eigs,
                          float* __restrict__ io,     // d_out accumulator
                          bf16* __restrict__ yb,
                          bf16* __restrict__ eb,
                          float* __restrict__ d0,
                          float* __restrict__ d1)
{
    const int wave = (int)((blockIdx.x * blockDim.x + threadIdx.x) >> 6);
    const int lane = (int)(threadIdx.x & 63);
    if (wave >= NN) return;
    const size_t idx = (size_t)wave * HD + lane;

    const float e0i = (wave < NU) ? user_emb[idx]
                                  : item_emb[idx - (size_t)NU * HD];
    const float x = FIRST ? e0i : io[idx];

    float s = x, sq = x * x;
#pragma unroll
    for (int o = 32; o; o >>= 1) {
        s  += __shfl_xor(s, o, 64);
        sq += __shfl_xor(sq, o, 64);
    }
    const float mu  = s * (1.0f / 64.0f);
    const float var = sq * (1.0f / 64.0f) - mu * mu;
    const float inv = rsqrtf(var + 1e-5f);

    yb[idx] = __float2bfloat16((x - mu) * inv);
    if (FIRST) {
        io[idx] = 0.0f;                       // zero layer-1 accumulator
        if (lane < ED)                        // bf16 eig table, built once
            eb[(size_t)wave * ED + lane] =
                __float2bfloat16(eigs[(size_t)wave * ED + lane]);
    } else {
        io[idx] = (e0i + x) * (1.0f / 3.0f);  // (emb0 + out1)/3
    }
    if (lane == 0) { d0[wave] = 0.0f; d1[wave] = 0.0f; }
}

// ---------------------------------------------------------------------------
// Wave per edge: s0 = (y[r].y[c])/8 + exp(lam0)*(eig[r].eig[c]).
// Scores are bounded (rows layernormed, eig-dots <~30) so exp() can't
// overflow in fp32 — segment-max pass skipped (softmax shift-invariance).
// ---------------------------------------------------------------------------
__global__ void edge_score_kernel(const bf16* __restrict__ yb,
                                  const bf16* __restrict__ eb,
                                  const int* __restrict__ row,
                                  const int* __restrict__ col,
                                  const int* __restrict__ pt,
                                  const float* __restrict__ lambda0,
                                  const float* __restrict__ pemb,
                                  int layer,
                                  float* __restrict__ e0,
                                  float* __restrict__ d0,
                                  float* __restrict__ d1)
{
    const int lane = (int)(threadIdx.x & 63);
    const int wave = (int)((blockIdx.x * blockDim.x + threadIdx.x) >> 6);
    const int nw   = (int)((gridDim.x * blockDim.x) >> 6);
    const float lam = __expf(lambda0[layer]);

    for (int e = wave; e < NE; e += nw) {
        const int r = row[e];
        const int c = col[e];
        float p = b2f(yb[(size_t)r * HD + lane]) *
                  b2f(yb[(size_t)c * HD + lane]) * 0.125f;
        if (lane < ED) {
            p += lam * b2f(eb[(size_t)r * ED + lane]) *
                       b2f(eb[(size_t)c * ED + lane]);
        }
#pragma unroll
        for (int o = 32; o; o >>= 1) p += __shfl_xor(p, o, 64);
        if (lane == 0) {
            const float ex = __expf(p);
            e0[e] = ex;
            atomicAdd(&d0[r], ex);
            atomicAdd(&d1[r], __expf(pemb[layer * NP + pt[e]]));
        }
    }
}

// ---------------------------------------------------------------------------
// Wave per edge: a = 0.5*(e0/d0[r] + e1/d1[r]); out[r] += scale*a*y[c] via a
// 64-lane contiguous fp32 atomic burst (256 B/edge).
// ---------------------------------------------------------------------------
__global__ void edge_aggregate_kernel(const bf16* __restrict__ yb,
                                      const int* __restrict__ row,
                                      const int* __restrict__ col,
                                      const int* __restrict__ pt,
                                      const float* __restrict__ pemb,
                                      int layer, float scale,
                                      const float* __restrict__ e0,
                                      const float* __restrict__ d0,
                                      const float* __restrict__ d1,
                                      float* __restrict__ out)
{
    const int lane = (int)(threadIdx.x & 63);
    const int wave = (int)((blockIdx.x * blockDim.x + threadIdx.x) >> 6);
    const int nw   = (int)((gridDim.x * blockDim.x) >> 6);

    for (int e = wave; e < NE; e += nw) {
        const int r = row[e];
        const int c = col[e];
        float a = 0.0f;
        if (lane == 0) {
            const float e1 = __expf(pemb[layer * NP + pt[e]]);
            a = scale * 0.5f * (e0[e] / d0[r] + e1 / d1[r]);
        }
        a = __shfl(a, 0, 64);
        atomicAdd(&out[(size_t)r * HD + lane],
                  a * b2f(yb[(size_t)c * HD + lane]));
    }
}

extern "C" void kernel_launch(void* const* d_in, const int* in_sizes, int n_in,
                              void* d_out, int out_size, void* d_ws, size_t ws_size,
                              hipStream_t stream)
{
    const float* user_emb = (const float*)d_in[0];
    const float* item_emb = (const float*)d_in[1];
    const float* eigs     = (const float*)d_in[2];
    const float* lambda0  = (const float*)d_in[3];
    const float* pemb     = (const float*)d_in[4];
    const int*   indices  = (const int*)d_in[5];
    const int*   ptype    = (const int*)d_in[6];
    const int*   row = indices;
    const int*   col = indices + NE;

    float* out = (float*)d_out;                 // NN*HD fp32 persistent accum
    char*  ws  = (char*)d_ws;
    bf16*  yb  = (bf16*)ws;                     // NN*HD bf16 (38.4 MB)
    bf16*  eb  = yb + (size_t)NN * HD;          // NN*ED bf16 (9.6 MB)
    float* d0  = (float*)(eb + (size_t)NN * ED);// NN
    float* d1  = d0 + NN;                       // NN
    float* e0  = d1 + NN;                       // NE
    // total ws ~ 55 MB

    const dim3 blk(256);
    const int ln_grid   = (NN * 64 + 255) / 256;   // wave per row
    const int edge_grid = 4096;                    // 16384 waves, grid-stride

    // ---- layer 0 ----
    ln_kernel<true><<<ln_grid, blk, 0, stream>>>(user_emb, item_emb, eigs,
                                                 out, yb, eb, d0, d1);
    edge_score_kernel<<<edge_grid, blk, 0, stream>>>(yb, eb, row, col, ptype,
                                                     lambda0, pemb, 0, e0, d0, d1);
    edge_aggregate_kernel<<<edge_grid, blk, 0, stream>>>(yb, row, col, ptype, pemb,
                                                         0, 1.0f, e0, d0, d1, out);
    // ---- layer 1 (ln fuses d_out := (emb0 + out1)/3) ----
    ln_kernel<false><<<ln_grid, blk, 0, stream>>>(user_emb, item_emb, eigs,
                                                  out, yb, eb, d0, d1);
    edge_score_kernel<<<edge_grid, blk, 0, stream>>>(yb, eb, row, col, ptype,
                                                     lambda0, pemb, 1, e0, d0, d1);
    edge_aggregate_kernel<<<edge_grid, blk, 0, stream>>>(yb, row, col, ptype, pemb,
                                                         1, 1.0f / 3.0f, e0, d0, d1, out);
}

// Round 4
// 677.171 us; speedup vs baseline: 2.2429x; 2.2111x over previous
//
#include <hip/hip_runtime.h>
#include <hip/hip_bf16.h>

#define HD 64
#define ED 16
#define NU 100000
#define NI 200000
#define NN 300000
#define NE 1250000
#define NP 14
#define SCAN_CHUNK 1024
#define NB_SCAN ((NN + SCAN_CHUNK - 1) / SCAN_CHUNK)   // 293

typedef __hip_bfloat16 bf16;
typedef unsigned short ushort8v __attribute__((ext_vector_type(8)));

__device__ __forceinline__ float bf2f(unsigned short u) {
    union { unsigned int i; float f; } c; c.i = ((unsigned int)u) << 16; return c.f;
}

// ---------------------------------------------------------------------------
// LayerNorm, wave per row (lane = dim). Writes bf16 gather table yb.
// FIRST: x = concat(user,item); zero d_out (layer-1 accumulator); build bf16
//        eig table (reused by both layers).
// !FIRST: x = d_out[i] (layer-1 out); fuse d_out[i] = (emb0 + x)/3 so the
//        layer-2 attention adds agg/3 and leaves the final mean in d_out.
// ---------------------------------------------------------------------------
template <bool FIRST>
__global__ void ln_kernel(const float* __restrict__ user_emb,
                          const float* __restrict__ item_emb,
                          const float* __restrict__ eigs,
                          float* __restrict__ io,     // d_out accumulator
                          bf16* __restrict__ yb,
                          bf16* __restrict__ eb)
{
    const int wave = (int)((blockIdx.x * blockDim.x + threadIdx.x) >> 6);
    const int lane = (int)(threadIdx.x & 63);
    if (wave >= NN) return;
    const size_t idx = (size_t)wave * HD + lane;

    const float e0i = (wave < NU) ? user_emb[idx]
                                  : item_emb[idx - (size_t)NU * HD];
    const float x = FIRST ? e0i : io[idx];

    float s = x, sq = x * x;
#pragma unroll
    for (int o = 32; o; o >>= 1) {
        s  += __shfl_xor(s, o, 64);
        sq += __shfl_xor(sq, o, 64);
    }
    const float mu  = s * (1.0f / 64.0f);
    const float var = sq * (1.0f / 64.0f) - mu * mu;
    const float inv = rsqrtf(var + 1e-5f);

    yb[idx] = __float2bfloat16((x - mu) * inv);
    if (FIRST) {
        io[idx] = 0.0f;                       // zero layer-1 accumulator
        if (lane < ED)
            eb[(size_t)wave * ED + lane] =
                __float2bfloat16(eigs[(size_t)wave * ED + lane]);
    } else {
        io[idx] = (e0i + x) * (1.0f / 3.0f);  // (emb0 + out1)/3
    }
}

// ------------------------- CSR build: counting sort -------------------------
__global__ void hist_kernel(const int* __restrict__ row, int* __restrict__ cnt)
{
    const int i = blockIdx.x * blockDim.x + threadIdx.x;
    if (i < NE) atomicAdd(&cnt[row[i]], 1);
}

// per-block exclusive scan over 1024-element chunks (256 thr x 4 elems)
__global__ void scan1_kernel(const int* __restrict__ cnt,
                             int* __restrict__ rowptr,
                             int* __restrict__ bsum)
{
    __shared__ int s[256];
    const int tid  = threadIdx.x;
    const int base = blockIdx.x * SCAN_CHUNK + tid * 4;
    int v[4]; int t = 0;
#pragma unroll
    for (int j = 0; j < 4; ++j) {
        v[j] = (base + j < NN) ? cnt[base + j] : 0;
        t += v[j];
    }
    s[tid] = t;
    __syncthreads();
    for (int off = 1; off < 256; off <<= 1) {
        int x = (tid >= off) ? s[tid - off] : 0;
        __syncthreads();
        s[tid] += x;
        __syncthreads();
    }
    int running = (tid > 0) ? s[tid - 1] : 0;   // exclusive thread offset
#pragma unroll
    for (int j = 0; j < 4; ++j) {
        if (base + j < NN) rowptr[base + j] = running;
        running += v[j];
    }
    if (tid == 0) bsum[blockIdx.x] = s[255];
}

// exclusive scan of the 293 block sums (single block of 512)
__global__ void scan2_kernel(int* __restrict__ bsum)
{
    __shared__ int s[512];
    const int tid = threadIdx.x;
    const int v = (tid < NB_SCAN) ? bsum[tid] : 0;
    s[tid] = v;
    __syncthreads();
    for (int off = 1; off < 512; off <<= 1) {
        int x = (tid >= off) ? s[tid - off] : 0;
        __syncthreads();
        s[tid] += x;
        __syncthreads();
    }
    if (tid < NB_SCAN) bsum[tid] = s[tid] - v;  // exclusive
}

__global__ void addoff_kernel(int* __restrict__ rowptr,
                              int* __restrict__ wq,
                              const int* __restrict__ bsum)
{
    const int i = blockIdx.x * blockDim.x + threadIdx.x;
    if (i >= NN) return;
    const int rp = rowptr[i] + bsum[i / SCAN_CHUNK];
    rowptr[i] = rp;
    wq[i] = rp;
}

// pack col (<2^20) | pt<<20 into one int; order within a row is arbitrary
__global__ void scatter_kernel(const int* __restrict__ row,
                               const int* __restrict__ col,
                               const int* __restrict__ pt,
                               int* __restrict__ wq,
                               int* __restrict__ epacked)
{
    const int i = blockIdx.x * blockDim.x + threadIdx.x;
    if (i >= NE) return;
    const int pos = atomicAdd(&wq[row[i]], 1);
    epacked[pos] = col[i] | (pt[i] << 20);
}

// ---------------------------------------------------------------------------
// Fused attention, 8-lane group per row (exclusive owner -> NO atomics).
// Sweep 1: d0 = sum exp(s0), d1 = sum exp(pemb[pt]) in registers.
// Sweep 2: re-gather y[col] (L2-hot: per-group working set ~deg*160B),
//          recompute e0, accumulate output row in registers, plain store.
// Scores bounded (rows layernormed) -> exp() safe without segment-max.
// LAYER==1 epilogue: out[r] += agg/3 (out holds (emb0+out1)/3 from ln2).
// ---------------------------------------------------------------------------
template <int LAYER>
__global__ void attn_row_kernel(const bf16* __restrict__ yb,
                                const bf16* __restrict__ eb,
                                const int* __restrict__ rowptr,
                                const int* __restrict__ cnt,
                                const int* __restrict__ epacked,
                                const float* __restrict__ lambda0,
                                const float* __restrict__ pemb,
                                float* __restrict__ out)
{
    const int tid = blockIdx.x * blockDim.x + threadIdx.x;
    const int r   = tid >> 3;
    const int sub = tid & 7;
    if (r >= NN) return;
    const int deg = cnt[r];
    if (deg == 0) return;                 // empty segment: out row untouched
    const int start = rowptr[r];
    const float lam = __expf(lambda0[LAYER]);

    float yrf[8];
    {
        ushort8v u = *reinterpret_cast<const ushort8v*>(yb + (size_t)r * HD + sub * 8);
#pragma unroll
        for (int j = 0; j < 8; ++j) yrf[j] = bf2f(u[j]);
    }
    float erf[8];
    if (sub < 2) {
        ushort8v u = *reinterpret_cast<const ushort8v*>(eb + (size_t)r * ED + sub * 8);
#pragma unroll
        for (int j = 0; j < 8; ++j) erf[j] = bf2f(u[j]);
    }

    // ---- sweep 1: denominators ----
    float d0 = 0.0f, d1 = 0.0f;
    for (int k = 0; k < deg; ++k) {
        const int v = epacked[start + k];
        const int c = v & 0xFFFFF;
        const int p = v >> 20;
        ushort8v uc = *reinterpret_cast<const ushort8v*>(yb + (size_t)c * HD + sub * 8);
        float s = 0.0f;
#pragma unroll
        for (int j = 0; j < 8; ++j) s += yrf[j] * bf2f(uc[j]);
        s *= 0.125f;
        if (sub < 2) {
            ushort8v ec = *reinterpret_cast<const ushort8v*>(eb + (size_t)c * ED + sub * 8);
            float se = 0.0f;
#pragma unroll
            for (int j = 0; j < 8; ++j) se += erf[j] * bf2f(ec[j]);
            s += lam * se;
        }
        s += __shfl_xor(s, 1, 64);
        s += __shfl_xor(s, 2, 64);
        s += __shfl_xor(s, 4, 64);
        d0 += __expf(s);
        d1 += __expf(pemb[LAYER * NP + p]);
    }
    const float i0 = 0.5f / d0, i1 = 0.5f / d1;

    // ---- sweep 2: weighted aggregation (recompute e0; gathers L2-hot) ----
    float acc[8];
#pragma unroll
    for (int j = 0; j < 8; ++j) acc[j] = 0.0f;
    for (int k = 0; k < deg; ++k) {
        const int v = epacked[start + k];
        const int c = v & 0xFFFFF;
        const int p = v >> 20;
        ushort8v uc = *reinterpret_cast<const ushort8v*>(yb + (size_t)c * HD + sub * 8);
        float yc[8];
        float s = 0.0f;
#pragma unroll
        for (int j = 0; j < 8; ++j) { yc[j] = bf2f(uc[j]); s += yrf[j] * yc[j]; }
        s *= 0.125f;
        if (sub < 2) {
            ushort8v ec = *reinterpret_cast<const ushort8v*>(eb + (size_t)c * ED + sub * 8);
            float se = 0.0f;
#pragma unroll
            for (int j = 0; j < 8; ++j) se += erf[j] * bf2f(ec[j]);
            s += lam * se;
        }
        s += __shfl_xor(s, 1, 64);
        s += __shfl_xor(s, 2, 64);
        s += __shfl_xor(s, 4, 64);
        const float a = i0 * __expf(s) + i1 * __expf(pemb[LAYER * NP + p]);
#pragma unroll
        for (int j = 0; j < 8; ++j) acc[j] += a * yc[j];
    }

    float* orow = out + (size_t)r * HD + sub * 8;
    if (LAYER == 0) {
        *reinterpret_cast<float4*>(orow)     = make_float4(acc[0], acc[1], acc[2], acc[3]);
        *reinterpret_cast<float4*>(orow + 4) = make_float4(acc[4], acc[5], acc[6], acc[7]);
    } else {
        const float third = 1.0f / 3.0f;
        float4 lo = *reinterpret_cast<const float4*>(orow);
        float4 hi = *reinterpret_cast<const float4*>(orow + 4);
        lo.x += acc[0] * third; lo.y += acc[1] * third;
        lo.z += acc[2] * third; lo.w += acc[3] * third;
        hi.x += acc[4] * third; hi.y += acc[5] * third;
        hi.z += acc[6] * third; hi.w += acc[7] * third;
        *reinterpret_cast<float4*>(orow)     = lo;
        *reinterpret_cast<float4*>(orow + 4) = hi;
    }
}

extern "C" void kernel_launch(void* const* d_in, const int* in_sizes, int n_in,
                              void* d_out, int out_size, void* d_ws, size_t ws_size,
                              hipStream_t stream)
{
    const float* user_emb = (const float*)d_in[0];
    const float* item_emb = (const float*)d_in[1];
    const float* eigs     = (const float*)d_in[2];
    const float* lambda0  = (const float*)d_in[3];
    const float* pemb     = (const float*)d_in[4];
    const int*   indices  = (const int*)d_in[5];
    const int*   ptype    = (const int*)d_in[6];
    const int*   row = indices;
    const int*   col = indices + NE;

    float* out = (float*)d_out;                       // NN*HD fp32 accumulator
    char*  ws  = (char*)d_ws;
    bf16*  yb      = (bf16*)ws;                       // NN*HD bf16  (38.4 MB)
    bf16*  eb      = yb + (size_t)NN * HD;            // NN*ED bf16  ( 9.6 MB)
    int*   cnt     = (int*)(eb + (size_t)NN * ED);    // NN
    int*   rowptr  = cnt + NN;                        // NN
    int*   wq      = rowptr + NN;                     // NN
    int*   bsum    = wq + NN;                         // NB_SCAN
    int*   epacked = bsum + ((NB_SCAN + 63) & ~63);   // NE
    // total ws ~ 57 MB

    const dim3 blk(256);
    const int ln_grid   = (NN * 64 + 255) / 256;      // wave per row
    const int edge_grid = (NE + 255) / 256;           // thread per edge
    const int node_grid = (NN + 255) / 256;
    const int attn_grid = (NN * 8 + 255) / 256;       // 8-lane group per row

    // ---- CSR build (counting sort by target row) ----
    hipMemsetAsync(cnt, 0, (size_t)NN * sizeof(int), stream);
    hist_kernel<<<edge_grid, blk, 0, stream>>>(row, cnt);
    scan1_kernel<<<NB_SCAN, blk, 0, stream>>>(cnt, rowptr, bsum);
    scan2_kernel<<<1, 512, 0, stream>>>(bsum);
    addoff_kernel<<<node_grid, blk, 0, stream>>>(rowptr, wq, bsum);
    scatter_kernel<<<edge_grid, blk, 0, stream>>>(row, col, ptype, wq, epacked);

    // ---- layer 0 ----
    ln_kernel<true><<<ln_grid, blk, 0, stream>>>(user_emb, item_emb, eigs,
                                                 out, yb, eb);
    attn_row_kernel<0><<<attn_grid, blk, 0, stream>>>(yb, eb, rowptr, cnt,
                                                      epacked, lambda0, pemb, out);
    // ---- layer 1 (ln fuses d_out := (emb0 + out1)/3; attn adds agg/3) ----
    ln_kernel<false><<<ln_grid, blk, 0, stream>>>(user_emb, item_emb, eigs,
                                                  out, yb, eb);
    attn_row_kernel<1><<<attn_grid, blk, 0, stream>>>(yb, eb, rowptr, cnt,
                                                      epacked, lambda0, pemb, out);
}

// Round 5
// 551.386 us; speedup vs baseline: 2.7546x; 1.2281x over previous
//
#include <hip/hip_runtime.h>
#include <hip/hip_bf16.h>

#define HD 64
#define ED 16
#define NU 100000
#define NI 200000
#define NN 300000
#define NE 1250000
#define NP 14
#define SCAN_CHUNK 1024
#define NB_SCAN ((NN + SCAN_CHUNK - 1) / SCAN_CHUNK)   // 293

typedef __hip_bfloat16 bf16;
typedef unsigned short ushort8v __attribute__((ext_vector_type(8)));

__device__ __forceinline__ float bf2f(unsigned short u) {
    union { unsigned int i; float f; } c; c.i = ((unsigned int)u) << 16; return c.f;
}

// ---------------------------------------------------------------------------
// LayerNorm, wave per row (lane = dim). Writes bf16 gather table yb.
// FIRST: x = concat(user,item); build bf16 eig table (reused by both layers).
//        (No out zero-init needed: attn<0> stores every row, incl. deg==0.)
// !FIRST: x = d_out[i] (layer-1 out); fuse d_out[i] = (emb0 + x)/3 so the
//        layer-2 attention adds agg/3 and leaves the final mean in d_out.
// ---------------------------------------------------------------------------
template <bool FIRST>
__global__ void ln_kernel(const float* __restrict__ user_emb,
                          const float* __restrict__ item_emb,
                          const float* __restrict__ eigs,
                          float* __restrict__ io,     // d_out accumulator
                          bf16* __restrict__ yb,
                          bf16* __restrict__ eb)
{
    const int wave = (int)((blockIdx.x * blockDim.x + threadIdx.x) >> 6);
    const int lane = (int)(threadIdx.x & 63);
    if (wave >= NN) return;
    const size_t idx = (size_t)wave * HD + lane;

    const float e0i = (wave < NU) ? user_emb[idx]
                                  : item_emb[idx - (size_t)NU * HD];
    const float x = FIRST ? e0i : io[idx];

    float s = x, sq = x * x;
#pragma unroll
    for (int o = 32; o; o >>= 1) {
        s  += __shfl_xor(s, o, 64);
        sq += __shfl_xor(sq, o, 64);
    }
    const float mu  = s * (1.0f / 64.0f);
    const float var = sq * (1.0f / 64.0f) - mu * mu;
    const float inv = rsqrtf(var + 1e-5f);

    yb[idx] = __float2bfloat16((x - mu) * inv);
    if (FIRST) {
        if (lane < ED)
            eb[(size_t)wave * ED + lane] =
                __float2bfloat16(eigs[(size_t)wave * ED + lane]);
    } else {
        io[idx] = (e0i + x) * (1.0f / 3.0f);  // (emb0 + out1)/3
    }
}

// ------------------------- CSR build: counting sort -------------------------
__global__ void hist_kernel(const int* __restrict__ row, int* __restrict__ cnt)
{
    const int i = blockIdx.x * blockDim.x + threadIdx.x;
    if (i < NE) atomicAdd(&cnt[row[i]], 1);
}

__global__ void scan1_kernel(const int* __restrict__ cnt,
                             int* __restrict__ rowptr,
                             int* __restrict__ bsum)
{
    __shared__ int s[256];
    const int tid  = threadIdx.x;
    const int base = blockIdx.x * SCAN_CHUNK + tid * 4;
    int v[4]; int t = 0;
#pragma unroll
    for (int j = 0; j < 4; ++j) {
        v[j] = (base + j < NN) ? cnt[base + j] : 0;
        t += v[j];
    }
    s[tid] = t;
    __syncthreads();
    for (int off = 1; off < 256; off <<= 1) {
        int x = (tid >= off) ? s[tid - off] : 0;
        __syncthreads();
        s[tid] += x;
        __syncthreads();
    }
    int running = (tid > 0) ? s[tid - 1] : 0;
#pragma unroll
    for (int j = 0; j < 4; ++j) {
        if (base + j < NN) rowptr[base + j] = running;
        running += v[j];
    }
    if (tid == 0) bsum[blockIdx.x] = s[255];
}

__global__ void scan2_kernel(int* __restrict__ bsum)
{
    __shared__ int s[512];
    const int tid = threadIdx.x;
    const int v = (tid < NB_SCAN) ? bsum[tid] : 0;
    s[tid] = v;
    __syncthreads();
    for (int off = 1; off < 512; off <<= 1) {
        int x = (tid >= off) ? s[tid - off] : 0;
        __syncthreads();
        s[tid] += x;
        __syncthreads();
    }
    if (tid < NB_SCAN) bsum[tid] = s[tid] - v;
}

__global__ void addoff_kernel(int* __restrict__ rowptr,
                              int* __restrict__ wq,
                              const int* __restrict__ bsum)
{
    const int i = blockIdx.x * blockDim.x + threadIdx.x;
    if (i >= NN) return;
    const int rp = rowptr[i] + bsum[i / SCAN_CHUNK];
    rowptr[i] = rp;
    wq[i] = rp;
}

// pack col (<2^19) | pt<<20; order within a row is arbitrary
__global__ void scatter_kernel(const int* __restrict__ row,
                               const int* __restrict__ col,
                               const int* __restrict__ pt,
                               int* __restrict__ wq,
                               int* __restrict__ epacked)
{
    const int i = blockIdx.x * blockDim.x + threadIdx.x;
    if (i >= NE) return;
    const int pos = atomicAdd(&wq[row[i]], 1);
    epacked[pos] = col[i] | (pt[i] << 20);
}

// ---------------------------------------------------------------------------
// Fused attention, SINGLE sweep, 8-lane group per row (exclusive owner).
// Normalization commutes with the sum:
//   out = 0.5*(sum e0*y[c])/d0 + 0.5*(sum e1*y[c])/d1
// so we keep unnormalized U0,U1 (+ scalars d0,d1) and divide once at the end
// -> half the gather traffic of the two-sweep version.
// epacked entries are staged 8-at-a-time into registers (coalesced) and
// broadcast via shfl, so gather addresses are known up-front (no dependent
// per-edge index load). Scores bounded (rows layernormed) -> exp() safe.
// LAYER 0: plain store (writes zeros when deg==0 -> no pre-zeroing of out).
// LAYER 1: out[r] += agg/3 (out holds (emb0+out1)/3 from ln<false>).
// ---------------------------------------------------------------------------
template <int LAYER>
__global__ void attn_row_kernel(const bf16* __restrict__ yb,
                                const bf16* __restrict__ eb,
                                const int* __restrict__ rowptr,
                                const int* __restrict__ cnt,
                                const int* __restrict__ epacked,
                                const float* __restrict__ lambda0,
                                const float* __restrict__ pemb,
                                float* __restrict__ out)
{
    const int tid  = blockIdx.x * blockDim.x + threadIdx.x;
    const int r    = tid >> 3;
    const int sub  = tid & 7;
    const int lane = (int)(threadIdx.x & 63);
    if (r >= NN) return;
    const int deg = cnt[r];
    float* orow = out + (size_t)r * HD + sub * 8;

    if (deg == 0) {                      // empty segment: segment_sum -> 0
        if (LAYER == 0) {
            *reinterpret_cast<float4*>(orow)     = make_float4(0, 0, 0, 0);
            *reinterpret_cast<float4*>(orow + 4) = make_float4(0, 0, 0, 0);
        }
        return;                          // LAYER 1: out already (emb0+out1)/3
    }

    const int start = rowptr[r];
    const float lam = __expf(lambda0[LAYER]);

    float yrf[8];
    {
        ushort8v u = *reinterpret_cast<const ushort8v*>(yb + (size_t)r * HD + sub * 8);
#pragma unroll
        for (int j = 0; j < 8; ++j) yrf[j] = bf2f(u[j]);
    }
    float erf[8];
    if (sub < 2) {
        ushort8v u = *reinterpret_cast<const ushort8v*>(eb + (size_t)r * ED + sub * 8);
#pragma unroll
        for (int j = 0; j < 8; ++j) erf[j] = bf2f(u[j]);
    }

    float U0[8], U1[8];
#pragma unroll
    for (int j = 0; j < 8; ++j) { U0[j] = 0.0f; U1[j] = 0.0f; }
    float d0 = 0.0f, d1 = 0.0f;

    int myv = (sub < deg) ? epacked[start + sub] : 0;   // stage first 8 edges
    for (int k = 0; k < deg; ++k) {
        const int kk = k & 7;
        if (k && kk == 0)                                // stage next 8
            myv = (k + sub < deg) ? epacked[start + k + sub] : 0;
        const int v = __shfl(myv, (lane & ~7) + kk, 64);
        const int c = v & 0xFFFFF;
        const int p = v >> 20;

        ushort8v uc = *reinterpret_cast<const ushort8v*>(yb + (size_t)c * HD + sub * 8);
        float yc[8];
        float s = 0.0f;
#pragma unroll
        for (int j = 0; j < 8; ++j) { yc[j] = bf2f(uc[j]); s += yrf[j] * yc[j]; }
        s *= 0.125f;
        if (sub < 2) {
            ushort8v ec = *reinterpret_cast<const ushort8v*>(eb + (size_t)c * ED + sub * 8);
            float se = 0.0f;
#pragma unroll
            for (int j = 0; j < 8; ++j) se += erf[j] * bf2f(ec[j]);
            s += lam * se;
        }
        s += __shfl_xor(s, 1, 64);
        s += __shfl_xor(s, 2, 64);
        s += __shfl_xor(s, 4, 64);

        const float e0 = __expf(s);
        const float e1 = __expf(pemb[LAYER * NP + p]);
        d0 += e0; d1 += e1;
#pragma unroll
        for (int j = 0; j < 8; ++j) {
            U0[j] += e0 * yc[j];
            U1[j] += e1 * yc[j];
        }
    }

    const float i0 = 0.5f / d0, i1 = 0.5f / d1;
    float acc[8];
#pragma unroll
    for (int j = 0; j < 8; ++j) acc[j] = i0 * U0[j] + i1 * U1[j];

    if (LAYER == 0) {
        *reinterpret_cast<float4*>(orow)     = make_float4(acc[0], acc[1], acc[2], acc[3]);
        *reinterpret_cast<float4*>(orow + 4) = make_float4(acc[4], acc[5], acc[6], acc[7]);
    } else {
        const float third = 1.0f / 3.0f;
        float4 lo = *reinterpret_cast<const float4*>(orow);
        float4 hi = *reinterpret_cast<const float4*>(orow + 4);
        lo.x += acc[0] * third; lo.y += acc[1] * third;
        lo.z += acc[2] * third; lo.w += acc[3] * third;
        hi.x += acc[4] * third; hi.y += acc[5] * third;
        hi.z += acc[6] * third; hi.w += acc[7] * third;
        *reinterpret_cast<float4*>(orow)     = lo;
        *reinterpret_cast<float4*>(orow + 4) = hi;
    }
}

extern "C" void kernel_launch(void* const* d_in, const int* in_sizes, int n_in,
                              void* d_out, int out_size, void* d_ws, size_t ws_size,
                              hipStream_t stream)
{
    const float* user_emb = (const float*)d_in[0];
    const float* item_emb = (const float*)d_in[1];
    const float* eigs     = (const float*)d_in[2];
    const float* lambda0  = (const float*)d_in[3];
    const float* pemb     = (const float*)d_in[4];
    const int*   indices  = (const int*)d_in[5];
    const int*   ptype    = (const int*)d_in[6];
    const int*   row = indices;
    const int*   col = indices + NE;

    float* out = (float*)d_out;                       // NN*HD fp32 accumulator
    char*  ws  = (char*)d_ws;
    bf16*  yb      = (bf16*)ws;                       // NN*HD bf16  (38.4 MB)
    bf16*  eb      = yb + (size_t)NN * HD;            // NN*ED bf16  ( 9.6 MB)
    int*   cnt     = (int*)(eb + (size_t)NN * ED);    // NN
    int*   rowptr  = cnt + NN;                        // NN
    int*   wq      = rowptr + NN;                     // NN
    int*   bsum    = wq + NN;                         // NB_SCAN
    int*   epacked = bsum + ((NB_SCAN + 63) & ~63);   // NE
    // total ws ~ 57 MB

    const dim3 blk(256);
    const int ln_grid   = (NN * 64 + 255) / 256;      // wave per row
    const int edge_grid = (NE + 255) / 256;           // thread per edge
    const int node_grid = (NN + 255) / 256;
    const int attn_grid = (NN * 8 + 255) / 256;       // 8-lane group per row

    // ---- CSR build (counting sort by target row) ----
    hipMemsetAsync(cnt, 0, (size_t)NN * sizeof(int), stream);
    hist_kernel<<<edge_grid, blk, 0, stream>>>(row, cnt);
    scan1_kernel<<<NB_SCAN, blk, 0, stream>>>(cnt, rowptr, bsum);
    scan2_kernel<<<1, 512, 0, stream>>>(bsum);
    addoff_kernel<<<node_grid, blk, 0, stream>>>(rowptr, wq, bsum);
    scatter_kernel<<<edge_grid, blk, 0, stream>>>(row, col, ptype, wq, epacked);

    // ---- layer 0 ----
    ln_kernel<true><<<ln_grid, blk, 0, stream>>>(user_emb, item_emb, eigs,
                                                 out, yb, eb);
    attn_row_kernel<0><<<attn_grid, blk, 0, stream>>>(yb, eb, rowptr, cnt,
                                                      epacked, lambda0, pemb, out);
    // ---- layer 1 (ln fuses d_out := (emb0 + out1)/3; attn adds agg/3) ----
    ln_kernel<false><<<ln_grid, blk, 0, stream>>>(user_emb, item_emb, eigs,
                                                  out, yb, eb);
    attn_row_kernel<1><<<attn_grid, blk, 0, stream>>>(yb, eb, rowptr, cnt,
                                                      epacked, lambda0, pemb, out);
}

// Round 6
// 414.009 us; speedup vs baseline: 3.6686x; 1.3318x over previous
//
#include <hip/hip_runtime.h>
#include <hip/hip_bf16.h>

#define HD 64
#define ED 16
#define NU 100000
#define NI 200000
#define NN 300000
#define NE 1250000
#define NP 14

#define RB 512                         // rows per bucket (9 bits)
#define NBKT ((NN + RB - 1) / RB)      // 586 buckets
#define A_ITEMS 8
#define A_CHUNK (256 * A_ITEMS)        // 2048 edges per binning block
#define A_BLOCKS ((NE + A_CHUNK - 1) / A_CHUNK)   // 611

typedef __hip_bfloat16 bf16;
typedef unsigned short ushort8v __attribute__((ext_vector_type(8)));

__device__ __forceinline__ float bf2f(unsigned short u) {
    union { unsigned int i; float f; } c; c.i = ((unsigned int)u) << 16; return c.f;
}
__device__ __forceinline__ unsigned short f2b(float x) {
    bf16 h = __float2bfloat16(x);
    unsigned short u; __builtin_memcpy(&u, &h, 2); return u;
}

// ---------------------------------------------------------------------------
// LayerNorm of the input embeddings, wave per row (lane = dim) -> bf16 yb.
// ---------------------------------------------------------------------------
__global__ void ln_kernel(const float* __restrict__ user_emb,
                          const float* __restrict__ item_emb,
                          bf16* __restrict__ yb)
{
    const int wave = (int)((blockIdx.x * blockDim.x + threadIdx.x) >> 6);
    const int lane = (int)(threadIdx.x & 63);
    if (wave >= NN) return;
    const size_t idx = (size_t)wave * HD + lane;
    const float x = (wave < NU) ? user_emb[idx] : item_emb[idx - (size_t)NU * HD];

    float s = x, sq = x * x;
#pragma unroll
    for (int o = 32; o; o >>= 1) {
        s  += __shfl_xor(s, o, 64);
        sq += __shfl_xor(sq, o, 64);
    }
    const float mu  = s * (1.0f / 64.0f);
    const float var = sq * (1.0f / 64.0f) - mu * mu;
    yb[idx] = __float2bfloat16((x - mu) * rsqrtf(var + 1e-5f));
}

// ------------------- CSR build, stage A1: bucket histogram ------------------
__global__ void bkt_count_kernel(const int* __restrict__ row,
                                 int* __restrict__ bkt_cnt)
{
    __shared__ int hist[NBKT];
    const int tid = threadIdx.x;
    for (int j = tid; j < NBKT; j += 256) hist[j] = 0;
    __syncthreads();
    const int base = blockIdx.x * A_CHUNK;
#pragma unroll
    for (int i = 0; i < A_ITEMS; ++i) {
        const int idx = base + i * 256 + tid;
        if (idx < NE) atomicAdd(&hist[row[idx] >> 9], 1);
    }
    __syncthreads();
    for (int j = tid; j < NBKT; j += 256) {
        const int h = hist[j];
        if (h) atomicAdd(&bkt_cnt[j], h);
    }
}

// ------------- stage A2: exclusive scan of bucket counts (1 blk) -----------
__global__ void bkt_scan_kernel(const int* __restrict__ bkt_cnt,
                                int* __restrict__ bkt_base,
                                int* __restrict__ wq_bkt)
{
    __shared__ int s[1024];
    const int t = threadIdx.x;
    const int v = (t < NBKT) ? bkt_cnt[t] : 0;
    s[t] = v;
    __syncthreads();
    for (int off = 1; off < 1024; off <<= 1) {
        int x = (t >= off) ? s[t - off] : 0;
        __syncthreads();
        s[t] += x;
        __syncthreads();
    }
    if (t < NBKT) {
        const int excl = s[t] - v;
        bkt_base[t] = excl;
        wq_bkt[t]   = excl;
        if (t == NBKT - 1) bkt_base[NBKT] = s[t];   // == NE
    }
}

// --------- stage A3: bin edges into buckets (packed 4-B pairs) -------------
// pair = col | pt<<19 | (row & 511)<<23  (col<2^19, pt<14, rowlow 9 bits)
__global__ void bkt_scatter_kernel(const int* __restrict__ row,
                                   const int* __restrict__ col,
                                   const int* __restrict__ pt,
                                   int* __restrict__ wq_bkt,
                                   int* __restrict__ pairs)
{
    __shared__ int hist[NBKT];
    __shared__ int rbase[NBKT];
    __shared__ int roff[NBKT];
    const int tid = threadIdx.x;
    for (int j = tid; j < NBKT; j += 256) { hist[j] = 0; roff[j] = 0; }
    __syncthreads();

    const int base = blockIdx.x * A_CHUNK;
    int vals[A_ITEMS], bkts[A_ITEMS];
#pragma unroll
    for (int i = 0; i < A_ITEMS; ++i) {
        const int idx = base + i * 256 + tid;
        bkts[i] = -1;
        if (idx < NE) {
            const int r = row[idx];
            vals[i] = col[idx] | (pt[idx] << 19) | ((r & (RB - 1)) << 23);
            bkts[i] = r >> 9;
            atomicAdd(&hist[bkts[i]], 1);
        }
    }
    __syncthreads();
    for (int j = tid; j < NBKT; j += 256) {
        const int h = hist[j];
        if (h) rbase[j] = atomicAdd(&wq_bkt[j], h);
    }
    __syncthreads();
#pragma unroll
    for (int i = 0; i < A_ITEMS; ++i) {
        if (bkts[i] >= 0) {
            const int o = atomicAdd(&roff[bkts[i]], 1);
            pairs[rbase[bkts[i]] + o] = vals[i];
        }
    }
}

// --------- stage B: per-bucket sort by row + eig-dot precompute ------------
// One block per bucket. Output: rowptr/cnt for the bucket's rows (coalesced),
// epacked int2 { col|pt<<19, eigdot(fp32) } written into a ~17-KB window.
__global__ void bkt_sort_kernel(const int* __restrict__ bkt_base,
                                const int* __restrict__ pairs,
                                const float* __restrict__ eigs,
                                int* __restrict__ rowptr,
                                int* __restrict__ cnt,
                                int2* __restrict__ epacked)
{
    __shared__ int rcnt[RB], lrp[RB], wq2[RB], ssum[256];
    __shared__ float estage[RB * ED];
    const int tid = threadIdx.x;
    const int b   = blockIdx.x;
    const int r0  = b * RB;
    const int s   = bkt_base[b];
    const int e   = bkt_base[b + 1];

    // phase 1: zero counters, stage this bucket's row-eigs
    for (int j = tid; j < RB; j += 256) { rcnt[j] = 0; wq2[j] = 0; }
    for (int k = tid; k < RB * ED; k += 256) {
        const int g = r0 * ED + k;
        estage[k] = (g < NN * ED) ? eigs[g] : 0.0f;
    }
    __syncthreads();

    // phase 2: row histogram
    for (int i = s + tid; i < e; i += 256)
        atomicAdd(&rcnt[(pairs[i] >> 23) & (RB - 1)], 1);
    __syncthreads();

    // phase 3: exclusive scan of 512 row counts (2 per thread)
    const int a0 = rcnt[2 * tid], a1 = rcnt[2 * tid + 1];
    ssum[tid] = a0 + a1;
    __syncthreads();
    for (int off = 1; off < 256; off <<= 1) {
        int x = (tid >= off) ? ssum[tid - off] : 0;
        __syncthreads();
        ssum[tid] += x;
        __syncthreads();
    }
    const int excl = ssum[tid] - (a0 + a1);
    lrp[2 * tid]     = excl;
    lrp[2 * tid + 1] = excl + a0;
    {
        const int r = r0 + 2 * tid;
        if (r < NN)     { rowptr[r]     = s + excl;      cnt[r]     = a0; }
        if (r + 1 < NN) { rowptr[r + 1] = s + excl + a0; cnt[r + 1] = a1; }
    }
    __syncthreads();

    // phase 4: scatter into row order + eig dot (row side from LDS)
    for (int i = s + tid; i < e; i += 256) {
        const int v  = pairs[i];
        const int rl = (v >> 23) & (RB - 1);
        const int c  = v & 0x7FFFF;
        const float4* ep = (const float4*)(eigs + (size_t)c * ED);
        const float4 q0 = ep[0], q1 = ep[1], q2 = ep[2], q3 = ep[3];
        const float* er = estage + rl * ED;
        float d = q0.x * er[0]  + q0.y * er[1]  + q0.z * er[2]  + q0.w * er[3]
                + q1.x * er[4]  + q1.y * er[5]  + q1.z * er[6]  + q1.w * er[7]
                + q2.x * er[8]  + q2.y * er[9]  + q2.z * er[10] + q2.w * er[11]
                + q3.x * er[12] + q3.y * er[13] + q3.z * er[14] + q3.w * er[15];
        const int o   = atomicAdd(&wq2[rl], 1);
        const int pos = s + lrp[rl] + o;
        epacked[pos] = make_int2(v & 0x7FFFFF, __float_as_int(d));
    }
}

// ---------------------------------------------------------------------------
// Fused attention, single sweep, 8-lane group per row (exclusive owner).
//   out = 0.5*(sum e0*y[c])/d0 + 0.5*(sum e1*y[c])/d1  (normalization
// commutes with the sum -> unnormalized U0,U1 + scalars d0,d1).
// epacked staged 8-entries-at-a-time, broadcast via shfl. Scores bounded
// (rows layernormed) -> exp() safe without segment-max.
// LAYER 0 epilogue: LayerNorm(out1) in-register -> yb_next (bf16) and
//   io = (emb0 + out1)/3.  (out1 never touches HBM; replaces ln2 kernel.)
// LAYER 1 epilogue: io += out2/3  -> final mean in d_out.
// ---------------------------------------------------------------------------
template <int LAYER>
__global__ void attn_row_kernel(const bf16* __restrict__ yb,
                                const int* __restrict__ rowptr,
                                const int* __restrict__ cnt,
                                const int2* __restrict__ epacked,
                                const float* __restrict__ lambda0,
                                const float* __restrict__ pemb,
                                const float* __restrict__ user_emb,
                                const float* __restrict__ item_emb,
                                bf16* __restrict__ yb_next,
                                float* __restrict__ io)
{
    __shared__ float e1tab[NP];
    if (threadIdx.x < NP)
        e1tab[threadIdx.x] = __expf(pemb[LAYER * NP + threadIdx.x]);
    __syncthreads();

    const int tid  = blockIdx.x * blockDim.x + threadIdx.x;
    const int r    = tid >> 3;
    const int sub  = tid & 7;
    const int lane = (int)(threadIdx.x & 63);
    if (r >= NN) return;
    const int deg = cnt[r];
    if (LAYER == 1 && deg == 0) return;   // out2 row = 0: io unchanged

    const int start = rowptr[r];
    const float lam = __expf(lambda0[LAYER]);

    float yrf[8];
    {
        ushort8v u = *reinterpret_cast<const ushort8v*>(yb + (size_t)r * HD + sub * 8);
#pragma unroll
        for (int j = 0; j < 8; ++j) yrf[j] = bf2f(u[j]);
    }

    float U0[8], U1[8];
#pragma unroll
    for (int j = 0; j < 8; ++j) { U0[j] = 0.0f; U1[j] = 0.0f; }
    float d0 = 0.0f, d1 = 0.0f;

    int2 myv = (sub < deg) ? epacked[start + sub] : make_int2(0, 0);
    for (int k = 0; k < deg; ++k) {
        const int kk = k & 7;
        if (k && kk == 0)
            myv = (k + sub < deg) ? epacked[start + k + sub] : make_int2(0, 0);
        const int src = (lane & ~7) + kk;
        const int   v    = __shfl(myv.x, src, 64);
        const float edot = __int_as_float(__shfl(myv.y, src, 64));
        const int c = v & 0x7FFFF;
        const int p = (v >> 19) & 15;

        ushort8v uc = *reinterpret_cast<const ushort8v*>(yb + (size_t)c * HD + sub * 8);
        float yc[8];
        float sdot = 0.0f;
#pragma unroll
        for (int j = 0; j < 8; ++j) { yc[j] = bf2f(uc[j]); sdot += yrf[j] * yc[j]; }
        sdot += __shfl_xor(sdot, 1, 64);
        sdot += __shfl_xor(sdot, 2, 64);
        sdot += __shfl_xor(sdot, 4, 64);

        const float e0 = __expf(sdot * 0.125f + lam * edot);
        const float e1 = e1tab[p];
        d0 += e0; d1 += e1;
#pragma unroll
        for (int j = 0; j < 8; ++j) {
            U0[j] += e0 * yc[j];
            U1[j] += e1 * yc[j];
        }
    }

    const float i0 = deg ? 0.5f / d0 : 0.0f;
    const float i1 = deg ? 0.5f / d1 : 0.0f;
    float acc[8];
#pragma unroll
    for (int j = 0; j < 8; ++j) acc[j] = i0 * U0[j] + i1 * U1[j];

    float* iorow = io + (size_t)r * HD + sub * 8;
    if (LAYER == 0) {
        // --- fused LayerNorm of out1 (acc) -> yb_next ---
        float sm = 0.0f, sq = 0.0f;
#pragma unroll
        for (int j = 0; j < 8; ++j) { sm += acc[j]; sq += acc[j] * acc[j]; }
        sm += __shfl_xor(sm, 1, 64); sq += __shfl_xor(sq, 1, 64);
        sm += __shfl_xor(sm, 2, 64); sq += __shfl_xor(sq, 2, 64);
        sm += __shfl_xor(sm, 4, 64); sq += __shfl_xor(sq, 4, 64);
        const float mu  = sm * (1.0f / 64.0f);
        const float var = sq * (1.0f / 64.0f) - mu * mu;
        const float inv = rsqrtf(var + 1e-5f);
        ushort8v w;
#pragma unroll
        for (int j = 0; j < 8; ++j) w[j] = f2b((acc[j] - mu) * inv);
        *reinterpret_cast<ushort8v*>(yb_next + (size_t)r * HD + sub * 8) = w;

        // --- io = (emb0 + out1)/3 ---
        const float* e0p = (r < NU) ? user_emb + (size_t)r * HD + sub * 8
                                    : item_emb + (size_t)(r - NU) * HD + sub * 8;
        const float4 lo = *reinterpret_cast<const float4*>(e0p);
        const float4 hi = *reinterpret_cast<const float4*>(e0p + 4);
        const float third = 1.0f / 3.0f;
        *reinterpret_cast<float4*>(iorow) =
            make_float4((lo.x + acc[0]) * third, (lo.y + acc[1]) * third,
                        (lo.z + acc[2]) * third, (lo.w + acc[3]) * third);
        *reinterpret_cast<float4*>(iorow + 4) =
            make_float4((hi.x + acc[4]) * third, (hi.y + acc[5]) * third,
                        (hi.z + acc[6]) * third, (hi.w + acc[7]) * third);
    } else {
        const float third = 1.0f / 3.0f;
        float4 lo = *reinterpret_cast<const float4*>(iorow);
        float4 hi = *reinterpret_cast<const float4*>(iorow + 4);
        lo.x += acc[0] * third; lo.y += acc[1] * third;
        lo.z += acc[2] * third; lo.w += acc[3] * third;
        hi.x += acc[4] * third; hi.y += acc[5] * third;
        hi.z += acc[6] * third; hi.w += acc[7] * third;
        *reinterpret_cast<float4*>(iorow)     = lo;
        *reinterpret_cast<float4*>(iorow + 4) = hi;
    }
}

extern "C" void kernel_launch(void* const* d_in, const int* in_sizes, int n_in,
                              void* d_out, int out_size, void* d_ws, size_t ws_size,
                              hipStream_t stream)
{
    const float* user_emb = (const float*)d_in[0];
    const float* item_emb = (const float*)d_in[1];
    const float* eigs     = (const float*)d_in[2];
    const float* lambda0  = (const float*)d_in[3];
    const float* pemb     = (const float*)d_in[4];
    const int*   indices  = (const int*)d_in[5];
    const int*   ptype    = (const int*)d_in[6];
    const int*   row = indices;
    const int*   col = indices + NE;

    float* io = (float*)d_out;                        // NN*HD fp32 accumulator
    char*  ws = (char*)d_ws;
    bf16* yb       = (bf16*)ws;                       // 38.4 MB
    bf16* yb2      = yb + (size_t)NN * HD;            // 38.4 MB
    int*  pairs    = (int*)(yb2 + (size_t)NN * HD);   // NE     (5 MB)
    int2* epacked  = (int2*)(pairs + NE);             // NE int2 (10 MB)
    int*  rowptr   = (int*)(epacked + NE);            // NN
    int*  cnt      = rowptr + NN;                     // NN
    int*  bkt_cnt  = cnt + NN;                        // NBKT
    int*  bkt_base = bkt_cnt + NBKT;                  // NBKT+1
    int*  wq_bkt   = bkt_base + NBKT + 1;             // NBKT
    // total ws ~ 94 MB

    const dim3 blk(256);
    const int ln_grid   = (NN * 64) / 256;            // wave per row (exact)
    const int attn_grid = (NN * 8) / 256;             // 8-lane group per row

    // ---- CSR build: two-level binned counting sort ----
    hipMemsetAsync(bkt_cnt, 0, NBKT * sizeof(int), stream);
    bkt_count_kernel<<<A_BLOCKS, blk, 0, stream>>>(row, bkt_cnt);
    bkt_scan_kernel<<<1, 1024, 0, stream>>>(bkt_cnt, bkt_base, wq_bkt);
    bkt_scatter_kernel<<<A_BLOCKS, blk, 0, stream>>>(row, col, ptype, wq_bkt, pairs);
    bkt_sort_kernel<<<NBKT, blk, 0, stream>>>(bkt_base, pairs, eigs,
                                              rowptr, cnt, epacked);

    // ---- layer 0 (attn fuses ln2 + final-mean prep) ----
    ln_kernel<<<ln_grid, blk, 0, stream>>>(user_emb, item_emb, yb);
    attn_row_kernel<0><<<attn_grid, blk, 0, stream>>>(yb, rowptr, cnt, epacked,
                                                      lambda0, pemb, user_emb,
                                                      item_emb, yb2, io);
    // ---- layer 1 (adds out2/3 -> final mean in d_out) ----
    attn_row_kernel<1><<<attn_grid, blk, 0, stream>>>(yb2, rowptr, cnt, epacked,
                                                      lambda0, pemb, user_emb,
                                                      item_emb, nullptr, io);
}

// Round 7
// 381.029 us; speedup vs baseline: 3.9862x; 1.0866x over previous
//
#include <hip/hip_runtime.h>
#include <hip/hip_bf16.h>

#define HD 64
#define ED 16
#define NU 100000
#define NI 200000
#define NN 300000
#define NE 1250000
#define NP 14

#define RB 512                         // rows per bucket (9 bits)
#define NBKT ((NN + RB - 1) / RB)      // 586 buckets
#define A_ITEMS 16
#define A_CHUNK (256 * A_ITEMS)        // 4096 edges per binning block
#define A_BLOCKS ((NE + A_CHUNK - 1) / A_CHUNK)   // 306

typedef __hip_bfloat16 bf16;
typedef unsigned short ushort8v __attribute__((ext_vector_type(8)));

__device__ __forceinline__ float bf2f(unsigned short u) {
    union { unsigned int i; float f; } c; c.i = ((unsigned int)u) << 16; return c.f;
}
__device__ __forceinline__ unsigned short f2b(float x) {
    bf16 h = __float2bfloat16(x);
    unsigned short u; __builtin_memcpy(&u, &h, 2); return u;
}

// ---------------------------------------------------------------------------
// LayerNorm of input embeddings, 8-lane group per row (lane = 8 dims).
// Vectorized float4 loads + 3-level shuffle (8 rows/wave vs 1 for the old
// wave-per-row version -> latency-bound 67us -> HBM-bound ~22us).
// Also converts eigs -> bf16 eb (2 elems/lane, packed 4-B store).
// ---------------------------------------------------------------------------
__global__ void ln_kernel(const float* __restrict__ user_emb,
                          const float* __restrict__ item_emb,
                          const float* __restrict__ eigs,
                          bf16* __restrict__ yb,
                          bf16* __restrict__ eb)
{
    const int tid = blockIdx.x * blockDim.x + threadIdx.x;
    const int r   = tid >> 3;
    const int sub = tid & 7;
    if (r >= NN) return;
    const float* src = (r < NU) ? user_emb + (size_t)r * HD
                                : item_emb + (size_t)(r - NU) * HD;
    const float4 lo = *reinterpret_cast<const float4*>(src + sub * 8);
    const float4 hi = *reinterpret_cast<const float4*>(src + sub * 8 + 4);
    float x[8] = {lo.x, lo.y, lo.z, lo.w, hi.x, hi.y, hi.z, hi.w};

    float sm = 0.0f, sq = 0.0f;
#pragma unroll
    for (int j = 0; j < 8; ++j) { sm += x[j]; sq += x[j] * x[j]; }
    sm += __shfl_xor(sm, 1, 64); sq += __shfl_xor(sq, 1, 64);
    sm += __shfl_xor(sm, 2, 64); sq += __shfl_xor(sq, 2, 64);
    sm += __shfl_xor(sm, 4, 64); sq += __shfl_xor(sq, 4, 64);
    const float mu  = sm * (1.0f / 64.0f);
    const float var = sq * (1.0f / 64.0f) - mu * mu;
    const float inv = rsqrtf(var + 1e-5f);

    ushort8v w;
#pragma unroll
    for (int j = 0; j < 8; ++j) w[j] = f2b((x[j] - mu) * inv);
    *reinterpret_cast<ushort8v*>(yb + (size_t)r * HD + sub * 8) = w;

    // bf16 eig table: 2 elems/lane, one packed 4-B store
    const float2 ev = *reinterpret_cast<const float2*>(eigs + (size_t)r * ED + sub * 2);
    const unsigned int packed = (unsigned int)f2b(ev.x) | ((unsigned int)f2b(ev.y) << 16);
    *reinterpret_cast<unsigned int*>(eb + (size_t)r * ED + sub * 2) = packed;
}

// ------------------- CSR build, stage A1: bucket histogram ------------------
__global__ void bkt_count_kernel(const int* __restrict__ row,
                                 int* __restrict__ bkt_cnt)
{
    __shared__ int hist[NBKT];
    const int tid = threadIdx.x;
    for (int j = tid; j < NBKT; j += 256) hist[j] = 0;
    __syncthreads();
    const int base = blockIdx.x * A_CHUNK;
#pragma unroll
    for (int i = 0; i < A_ITEMS; ++i) {
        const int idx = base + i * 256 + tid;
        if (idx < NE) atomicAdd(&hist[row[idx] >> 9], 1);
    }
    __syncthreads();
    for (int j = tid; j < NBKT; j += 256) {
        const int h = hist[j];
        if (h) atomicAdd(&bkt_cnt[j], h);
    }
}

// ------------- stage A2: exclusive scan of bucket counts (1 blk) -----------
__global__ void bkt_scan_kernel(const int* __restrict__ bkt_cnt,
                                int* __restrict__ bkt_base,
                                int* __restrict__ wq_bkt)
{
    __shared__ int s[1024];
    const int t = threadIdx.x;
    const int v = (t < NBKT) ? bkt_cnt[t] : 0;
    s[t] = v;
    __syncthreads();
    for (int off = 1; off < 1024; off <<= 1) {
        int x = (t >= off) ? s[t - off] : 0;
        __syncthreads();
        s[t] += x;
        __syncthreads();
    }
    if (t < NBKT) {
        const int excl = s[t] - v;
        bkt_base[t] = excl;
        wq_bkt[t]   = excl;
        if (t == NBKT - 1) bkt_base[NBKT] = s[t];   // == NE
    }
}

// --------- stage A3: bin edges into buckets (packed 4-B pairs) -------------
// pair = col | pt<<19 | (row & 511)<<23. Count pass -> block reservation ->
// scatter pass (re-reads inputs from L2 instead of holding 16 regs/thread).
__global__ void bkt_scatter_kernel(const int* __restrict__ row,
                                   const int* __restrict__ col,
                                   const int* __restrict__ pt,
                                   int* __restrict__ wq_bkt,
                                   int* __restrict__ pairs)
{
    __shared__ int hist[NBKT];
    __shared__ int rbase[NBKT];
    __shared__ int roff[NBKT];
    const int tid = threadIdx.x;
    for (int j = tid; j < NBKT; j += 256) { hist[j] = 0; roff[j] = 0; }
    __syncthreads();

    const int base = blockIdx.x * A_CHUNK;
#pragma unroll
    for (int i = 0; i < A_ITEMS; ++i) {
        const int idx = base + i * 256 + tid;
        if (idx < NE) atomicAdd(&hist[row[idx] >> 9], 1);
    }
    __syncthreads();
    for (int j = tid; j < NBKT; j += 256) {
        const int h = hist[j];
        if (h) rbase[j] = atomicAdd(&wq_bkt[j], h);
    }
    __syncthreads();
#pragma unroll
    for (int i = 0; i < A_ITEMS; ++i) {
        const int idx = base + i * 256 + tid;
        if (idx < NE) {
            const int r = row[idx];
            const int b = r >> 9;
            const int v = col[idx] | (pt[idx] << 19) | ((r & (RB - 1)) << 23);
            const int o = atomicAdd(&roff[b], 1);
            pairs[rbase[b] + o] = v;
        }
    }
}

// --------- stage B: per-bucket sort by row + eig-dot precompute ------------
// One block per bucket. Row-side eigs staged fp32 in LDS (coalesced read);
// col-side gathered bf16 (32 B/edge, half the fp32 traffic). Output:
// rowptr/cnt + epacked int2 { col|pt<<19, eigdot fp32 } in a ~17-KB window.
__global__ void bkt_sort_kernel(const int* __restrict__ bkt_base,
                                const int* __restrict__ pairs,
                                const float* __restrict__ eigs,
                                const bf16* __restrict__ eb,
                                int* __restrict__ rowptr,
                                int* __restrict__ cnt,
                                int2* __restrict__ epacked)
{
    __shared__ int rcnt[RB], lrp[RB], wq2[RB], ssum[256];
    __shared__ float estage[RB * ED];
    const int tid = threadIdx.x;
    const int b   = blockIdx.x;
    const int r0  = b * RB;
    const int s   = bkt_base[b];
    const int e   = bkt_base[b + 1];

    for (int j = tid; j < RB; j += 256) { rcnt[j] = 0; wq2[j] = 0; }
    for (int k = tid; k < RB * ED; k += 256) {
        const int g = r0 * ED + k;
        estage[k] = (g < NN * ED) ? eigs[g] : 0.0f;
    }
    __syncthreads();

    for (int i = s + tid; i < e; i += 256)
        atomicAdd(&rcnt[(pairs[i] >> 23) & (RB - 1)], 1);
    __syncthreads();

    const int a0 = rcnt[2 * tid], a1 = rcnt[2 * tid + 1];
    ssum[tid] = a0 + a1;
    __syncthreads();
    for (int off = 1; off < 256; off <<= 1) {
        int x = (tid >= off) ? ssum[tid - off] : 0;
        __syncthreads();
        ssum[tid] += x;
        __syncthreads();
    }
    const int excl = ssum[tid] - (a0 + a1);
    lrp[2 * tid]     = excl;
    lrp[2 * tid + 1] = excl + a0;
    {
        const int r = r0 + 2 * tid;
        if (r < NN)     { rowptr[r]     = s + excl;      cnt[r]     = a0; }
        if (r + 1 < NN) { rowptr[r + 1] = s + excl + a0; cnt[r + 1] = a1; }
    }
    __syncthreads();

    for (int i = s + tid; i < e; i += 256) {
        const int v  = pairs[i];
        const int rl = (v >> 23) & (RB - 1);
        const int c  = v & 0x7FFFF;
        const ushort8v* ep = reinterpret_cast<const ushort8v*>(eb + (size_t)c * ED);
        const ushort8v q0 = ep[0], q1 = ep[1];
        const float* er = estage + rl * ED;
        float d = 0.0f;
#pragma unroll
        for (int j = 0; j < 8; ++j) d += bf2f(q0[j]) * er[j];
#pragma unroll
        for (int j = 0; j < 8; ++j) d += bf2f(q1[j]) * er[j + 8];
        const int o   = atomicAdd(&wq2[rl], 1);
        const int pos = s + lrp[rl] + o;
        epacked[pos] = make_int2(v & 0x7FFFFF, __float_as_int(d));
    }
}

// ---------------------------------------------------------------------------
// Fused attention, single sweep, 8-lane group per row (exclusive owner).
//   out = 0.5*(sum e0*y[c])/d0 + 0.5*(sum e1*y[c])/d1
// epacked staged 8-entries-at-a-time, broadcast via shfl. Scores bounded
// (rows layernormed) -> exp() safe without segment-max.
// LAYER 0 epilogue: in-register LayerNorm(out1) -> yb_next; io=(emb0+out1)/3.
// LAYER 1 epilogue: io += out2/3 -> final mean in d_out.
// ---------------------------------------------------------------------------
template <int LAYER>
__global__ void attn_row_kernel(const bf16* __restrict__ yb,
                                const int* __restrict__ rowptr,
                                const int* __restrict__ cnt,
                                const int2* __restrict__ epacked,
                                const float* __restrict__ lambda0,
                                const float* __restrict__ pemb,
                                const float* __restrict__ user_emb,
                                const float* __restrict__ item_emb,
                                bf16* __restrict__ yb_next,
                                float* __restrict__ io)
{
    __shared__ float e1tab[NP];
    if (threadIdx.x < NP)
        e1tab[threadIdx.x] = __expf(pemb[LAYER * NP + threadIdx.x]);
    __syncthreads();

    const int tid  = blockIdx.x * blockDim.x + threadIdx.x;
    const int r    = tid >> 3;
    const int sub  = tid & 7;
    const int lane = (int)(threadIdx.x & 63);
    if (r >= NN) return;
    const int deg = cnt[r];
    if (LAYER == 1 && deg == 0) return;   // out2 row = 0: io unchanged

    const int start = rowptr[r];
    const float lam = __expf(lambda0[LAYER]);

    float yrf[8];
    {
        ushort8v u = *reinterpret_cast<const ushort8v*>(yb + (size_t)r * HD + sub * 8);
#pragma unroll
        for (int j = 0; j < 8; ++j) yrf[j] = bf2f(u[j]);
    }

    float U0[8], U1[8];
#pragma unroll
    for (int j = 0; j < 8; ++j) { U0[j] = 0.0f; U1[j] = 0.0f; }
    float d0 = 0.0f, d1 = 0.0f;

    int2 myv = (sub < deg) ? epacked[start + sub] : make_int2(0, 0);
    for (int k = 0; k < deg; ++k) {
        const int kk = k & 7;
        if (k && kk == 0)
            myv = (k + sub < deg) ? epacked[start + k + sub] : make_int2(0, 0);
        const int src = (lane & ~7) + kk;
        const int   v    = __shfl(myv.x, src, 64);
        const float edot = __int_as_float(__shfl(myv.y, src, 64));
        const int c = v & 0x7FFFF;
        const int p = (v >> 19) & 15;

        ushort8v uc = *reinterpret_cast<const ushort8v*>(yb + (size_t)c * HD + sub * 8);
        float yc[8];
        float sdot = 0.0f;
#pragma unroll
        for (int j = 0; j < 8; ++j) { yc[j] = bf2f(uc[j]); sdot += yrf[j] * yc[j]; }
        sdot += __shfl_xor(sdot, 1, 64);
        sdot += __shfl_xor(sdot, 2, 64);
        sdot += __shfl_xor(sdot, 4, 64);

        const float e0 = __expf(sdot * 0.125f + lam * edot);
        const float e1 = e1tab[p];
        d0 += e0; d1 += e1;
#pragma unroll
        for (int j = 0; j < 8; ++j) {
            U0[j] += e0 * yc[j];
            U1[j] += e1 * yc[j];
        }
    }

    const float i0 = deg ? 0.5f / d0 : 0.0f;
    const float i1 = deg ? 0.5f / d1 : 0.0f;
    float acc[8];
#pragma unroll
    for (int j = 0; j < 8; ++j) acc[j] = i0 * U0[j] + i1 * U1[j];

    float* iorow = io + (size_t)r * HD + sub * 8;
    if (LAYER == 0) {
        float sm = 0.0f, sq = 0.0f;
#pragma unroll
        for (int j = 0; j < 8; ++j) { sm += acc[j]; sq += acc[j] * acc[j]; }
        sm += __shfl_xor(sm, 1, 64); sq += __shfl_xor(sq, 1, 64);
        sm += __shfl_xor(sm, 2, 64); sq += __shfl_xor(sq, 2, 64);
        sm += __shfl_xor(sm, 4, 64); sq += __shfl_xor(sq, 4, 64);
        const float mu  = sm * (1.0f / 64.0f);
        const float var = sq * (1.0f / 64.0f) - mu * mu;
        const float inv = rsqrtf(var + 1e-5f);
        ushort8v w;
#pragma unroll
        for (int j = 0; j < 8; ++j) w[j] = f2b((acc[j] - mu) * inv);
        *reinterpret_cast<ushort8v*>(yb_next + (size_t)r * HD + sub * 8) = w;

        const float* e0p = (r < NU) ? user_emb + (size_t)r * HD + sub * 8
                                    : item_emb + (size_t)(r - NU) * HD + sub * 8;
        const float4 lo = *reinterpret_cast<const float4*>(e0p);
        const float4 hi = *reinterpret_cast<const float4*>(e0p + 4);
        const float third = 1.0f / 3.0f;
        *reinterpret_cast<float4*>(iorow) =
            make_float4((lo.x + acc[0]) * third, (lo.y + acc[1]) * third,
                        (lo.z + acc[2]) * third, (lo.w + acc[3]) * third);
        *reinterpret_cast<float4*>(iorow + 4) =
            make_float4((hi.x + acc[4]) * third, (hi.y + acc[5]) * third,
                        (hi.z + acc[6]) * third, (hi.w + acc[7]) * third);
    } else {
        const float third = 1.0f / 3.0f;
        float4 lo = *reinterpret_cast<const float4*>(iorow);
        float4 hi = *reinterpret_cast<const float4*>(iorow + 4);
        lo.x += acc[0] * third; lo.y += acc[1] * third;
        lo.z += acc[2] * third; lo.w += acc[3] * third;
        hi.x += acc[4] * third; hi.y += acc[5] * third;
        hi.z += acc[6] * third; hi.w += acc[7] * third;
        *reinterpret_cast<float4*>(iorow)     = lo;
        *reinterpret_cast<float4*>(iorow + 4) = hi;
    }
}

extern "C" void kernel_launch(void* const* d_in, const int* in_sizes, int n_in,
                              void* d_out, int out_size, void* d_ws, size_t ws_size,
                              hipStream_t stream)
{
    const float* user_emb = (const float*)d_in[0];
    const float* item_emb = (const float*)d_in[1];
    const float* eigs     = (const float*)d_in[2];
    const float* lambda0  = (const float*)d_in[3];
    const float* pemb     = (const float*)d_in[4];
    const int*   indices  = (const int*)d_in[5];
    const int*   ptype    = (const int*)d_in[6];
    const int*   row = indices;
    const int*   col = indices + NE;

    float* io = (float*)d_out;                        // NN*HD fp32 accumulator
    char*  ws = (char*)d_ws;
    bf16* yb       = (bf16*)ws;                       // 38.4 MB
    bf16* yb2      = yb + (size_t)NN * HD;            // 38.4 MB
    bf16* eb       = yb2 + (size_t)NN * HD;           //  9.6 MB
    int*  pairs    = (int*)(eb + (size_t)NN * ED);    // NE      (5 MB)
    int2* epacked  = (int2*)(pairs + NE);             // NE int2 (10 MB)
    int*  rowptr   = (int*)(epacked + NE);            // NN
    int*  cnt      = rowptr + NN;                     // NN
    int*  bkt_cnt  = cnt + NN;                        // NBKT
    int*  bkt_base = bkt_cnt + NBKT;                  // NBKT+1
    int*  wq_bkt   = bkt_base + NBKT + 1;             // NBKT
    // total ws ~ 104 MB

    const dim3 blk(256);
    const int grid8 = (NN * 8) / 256;                 // 8-lane group per row

    // ---- LayerNorm + bf16 eig table (eb consumed by bkt_sort) ----
    ln_kernel<<<grid8, blk, 0, stream>>>(user_emb, item_emb, eigs, yb, eb);

    // ---- CSR build: two-level binned counting sort ----
    hipMemsetAsync(bkt_cnt, 0, NBKT * sizeof(int), stream);
    bkt_count_kernel<<<A_BLOCKS, blk, 0, stream>>>(row, bkt_cnt);
    bkt_scan_kernel<<<1, 1024, 0, stream>>>(bkt_cnt, bkt_base, wq_bkt);
    bkt_scatter_kernel<<<A_BLOCKS, blk, 0, stream>>>(row, col, ptype, wq_bkt, pairs);
    bkt_sort_kernel<<<NBKT, blk, 0, stream>>>(bkt_base, pairs, eigs, eb,
                                              rowptr, cnt, epacked);

    // ---- layer 0 (attn fuses ln2 + final-mean prep) ----
    attn_row_kernel<0><<<grid8, blk, 0, stream>>>(yb, rowptr, cnt, epacked,
                                                  lambda0, pemb, user_emb,
                                                  item_emb, yb2, io);
    // ---- layer 1 (adds out2/3 -> final mean in d_out) ----
    attn_row_kernel<1><<<grid8, blk, 0, stream>>>(yb2, rowptr, cnt, epacked,
                                                  lambda0, pemb, user_emb,
                                                  item_emb, nullptr, io);
}